// Round 5
// baseline (15999.243 us; speedup 1.0000x reference)
//
#include <hip/hip_runtime.h>
#include <math.h>

#define H 1024
#define S 256
#define VOUT 32000
#define X4W 4096
#define G3 3072

__device__ __forceinline__ float wred_sum(float v){
#pragma unroll
  for(int o=32;o;o>>=1) v += __shfl_xor(v,o);
  return v;
}
__device__ __forceinline__ float wred_max(float v){
#pragma unroll
  for(int o=32;o;o>>=1) v = fmaxf(v,__shfl_xor(v,o));
  return v;
}
__device__ __forceinline__ float sigmoidf_(float x){ return 1.f/(1.f+expf(-x)); }

// ---------------------------------------------------------------- prep
// gathers embeddings, zeroes accumulators and h0
__global__ __launch_bounds__(256) void prep_kernel(
    const int* __restrict__ src, const int* __restrict__ tgt,
    const float* __restrict__ enc_emb, const float* __restrict__ dec_emb,
    float* __restrict__ x_emb, float* __restrict__ emb_all, float* __restrict__ x4,
    float* __restrict__ hbuf0, float* __restrict__ s_acc, float* __restrict__ enc_score){
  int t = blockIdx.x, tid = threadIdx.x;
  int st = src[t];
  int dt = (t==0) ? src[0] : tgt[t-1];
  float4 v = ((const float4*)(enc_emb + (size_t)st*H))[tid];
  ((float4*)(x_emb + (size_t)t*H))[tid] = v;
  float4 u = ((const float4*)(dec_emb + (size_t)dt*H))[tid];
  ((float4*)(emb_all + (size_t)t*H))[tid] = u;
  ((float4*)(x4 + (size_t)t*X4W))[tid] = u;
  if(t==0){
    s_acc[tid] = 0.f;                 // s_acc[0..255]; [256] is write-only junk
    if(tid==0) s_acc[S] = 0.f;
    enc_score[tid] = 0.f;
    for(int i=tid;i<2*H;i+=256) hbuf0[i]=0.f;
  }
}

// ---------------------------------------------------------------- SGEMM (NT, C stored transposed [n][m], bias over m)
#define BM 64
#define BN 64
#define BK 16
__global__ __launch_bounds__(256) void sgemm_nt_ct(
    const float* __restrict__ A, int lda,
    const float* __restrict__ B, int ldb,
    const float* __restrict__ bias,
    float* __restrict__ C, int ldc, int K){
  const int m0 = blockIdx.x * BM;
  const int n0 = blockIdx.y * BN;
  const int tid = threadIdx.x;
  const int tm = tid & 15;
  const int tn = tid >> 4;
  const int lr = tid >> 2;        // 0..63
  const int lk = (tid & 3) * 4;   // 0,4,8,12
  __shared__ float As[BK][BM+4];
  __shared__ float Bs[BK][BN+4];
  float acc[4][4] = {};
  for(int k0=0;k0<K;k0+=BK){
    float4 a = *(const float4*)(A + (size_t)(m0+lr)*lda + k0 + lk);
    float4 b = *(const float4*)(B + (size_t)(n0+lr)*ldb + k0 + lk);
    __syncthreads();
    As[lk+0][lr]=a.x; As[lk+1][lr]=a.y; As[lk+2][lr]=a.z; As[lk+3][lr]=a.w;
    Bs[lk+0][lr]=b.x; Bs[lk+1][lr]=b.y; Bs[lk+2][lr]=b.z; Bs[lk+3][lr]=b.w;
    __syncthreads();
#pragma unroll
    for(int kk=0;kk<BK;kk++){
      float av[4], bv[4];
#pragma unroll
      for(int i=0;i<4;i++) av[i]=As[kk][tm*4+i];
#pragma unroll
      for(int j=0;j<4;j++) bv[j]=Bs[kk][tn*4+j];
#pragma unroll
      for(int j=0;j<4;j++)
#pragma unroll
        for(int i=0;i<4;i++)
          acc[j][i] += av[i]*bv[j];
    }
  }
#pragma unroll
  for(int j=0;j<4;j++){
    int n = n0 + tn*4 + j;
#pragma unroll
    for(int i=0;i<4;i++){
      int m = m0 + tm*4 + i;
      C[(size_t)n*ldc + m] = acc[j][i] + bias[m];
    }
  }
}

// ---------------------------------------------------------------- encoder step
// 2048 waves: wave e<1024 -> fwd GRU element e; e>=1024 -> bwd GRU element e-1024
__global__ __launch_bounds__(256) void enc_step_kernel(
    int t,
    const float* __restrict__ Whh_f, const float* __restrict__ Whh_b,
    const float* __restrict__ bhh_f, const float* __restrict__ bhh_b,
    const float* __restrict__ gi_f, const float* __restrict__ gi_b,
    const float* __restrict__ hprev, float* __restrict__ hnext,
    float* __restrict__ enc_outsT, float* __restrict__ enc_score,
    const float* __restrict__ v_enc){
  int wave = (blockIdx.x*blockDim.x + threadIdx.x) >> 6;
  int lane = threadIdx.x & 63;
  bool isB = wave >= H;
  int i = isB ? wave - H : wave;
  const float* Whh = isB ? Whh_b : Whh_f;
  const float* bhh = isB ? bhh_b : bhh_f;
  const float* gi  = (isB ? gi_b : gi_f) + (size_t)t*G3;
  const float* h   = hprev + (isB ? H : 0);
  const float4* hv = (const float4*)h;
  const float4* r0 = (const float4*)(Whh + (size_t)i*H);
  const float4* r1 = (const float4*)(Whh + (size_t)(i+H)*H);
  const float4* r2 = (const float4*)(Whh + (size_t)(i+2*H)*H);
  float d0=0,d1=0,d2=0;
#pragma unroll
  for(int k=lane;k<H/4;k+=64){
    float4 hh = hv[k];
    float4 a = r0[k]; d0 += a.x*hh.x+a.y*hh.y+a.z*hh.z+a.w*hh.w;
    float4 b = r1[k]; d1 += b.x*hh.x+b.y*hh.y+b.z*hh.z+b.w*hh.w;
    float4 c = r2[k]; d2 += c.x*hh.x+c.y*hh.y+c.z*hh.z+c.w*hh.w;
  }
  d0=wred_sum(d0); d1=wred_sum(d1); d2=wred_sum(d2);
  if(lane==0){
    float r = sigmoidf_(gi[i]       + d0 + bhh[i]);
    float z = sigmoidf_(gi[i+H]     + d1 + bhh[i+H]);
    float n = tanhf    (gi[i+2*H]   + r*(d2 + bhh[i+2*H]));
    float hn_ = (1.f-z)*n + z*h[i];
    hnext[(isB?H:0) + i] = hn_;
    enc_outsT[(size_t)wave*S + t] = hn_;
    atomicAdd(&enc_score[t], hn_ * v_enc[wave]);
  }
}

// ---------------------------------------------------------------- dec_h0 = fcW @ hb_T + fcb ; s[0] = dec_h0 . v_dec
__global__ __launch_bounds__(256) void dec_h0_kernel(
    const float* __restrict__ fcW, const float* __restrict__ fcb,
    const float* __restrict__ hbT, float* __restrict__ dh0,
    float* __restrict__ s_acc, const float* __restrict__ v_dec){
  int wave = (blockIdx.x*blockDim.x + threadIdx.x) >> 6;
  int lane = threadIdx.x & 63;
  const float4* rv = (const float4*)(fcW + (size_t)wave*H);
  const float4* hv = (const float4*)hbT;
  float d=0;
#pragma unroll
  for(int k=lane;k<H/4;k+=64){
    float4 a=rv[k], h=hv[k];
    d += a.x*h.x+a.y*h.y+a.z*h.z+a.w*h.w;
  }
  d = wred_sum(d);
  if(lane==0){
    float val = d + fcb[wave];
    dh0[wave]=val;
    atomicAdd(&s_acc[0], val*v_dec[wave]);
  }
}

// ---------------------------------------------------------------- decoder attention/ctx
// each block: redundant softmax over 256 energies, then 32 ctx elements
__global__ __launch_bounds__(256) void dec_ctx_kernel(
    int t, const float* __restrict__ s_acc, const float* __restrict__ enc_score,
    const float* __restrict__ enc_outsT, float* __restrict__ x4){
  __shared__ float attn[S];
  __shared__ float wtA[4];
  __shared__ float wtB[4];
  int tid=threadIdx.x, lane=tid&63, w=tid>>6;
  float sc = s_acc[t];
  float e = tanhf(sc + enc_score[tid]);
  float m = wred_max(e);
  if(lane==0) wtA[w]=m;
  __syncthreads();
  float M = fmaxf(fmaxf(wtA[0],wtA[1]),fmaxf(wtA[2],wtA[3]));
  float ex = expf(e-M);
  float s1 = wred_sum(ex);
  if(lane==0) wtB[w]=s1;
  __syncthreads();
  float Z = wtB[0]+wtB[1]+wtB[2]+wtB[3];
  attn[tid] = ex/Z;
  __syncthreads();
  float4 at = *(const float4*)&attn[lane*4];
#pragma unroll
  for(int kk=0;kk<8;kk++){
    int k = blockIdx.x*32 + w*8 + kk;
    float4 a = ((const float4*)(enc_outsT + (size_t)k*S))[lane];
    float p = a.x*at.x + a.y*at.y + a.z*at.z + a.w*at.w;
    p = wred_sum(p);
    if(lane==0) x4[(size_t)t*X4W + H + k] = p;
  }
}

// ---------------------------------------------------------------- decoder GRU step
// 1024 waves, one per h element
__global__ __launch_bounds__(256) void dec_gru_kernel(
    int t, const float* __restrict__ Wih, const float* __restrict__ Whh,
    const float* __restrict__ gie, const float* __restrict__ bhh,
    const float* __restrict__ hprev, float* __restrict__ hnext,
    float* __restrict__ x4, float* __restrict__ s_acc,
    const float* __restrict__ v_dec){
  int wave = (blockIdx.x*blockDim.x + threadIdx.x) >> 6;
  int lane = threadIdx.x & 63;
  int i = wave;
  const float* ctx = x4 + (size_t)t*X4W + H;
  const float4* cv = (const float4*)ctx;
  const float4* hv = (const float4*)hprev;
  const float4* w0 = (const float4*)(Wih + (size_t)i*G3 + H);
  const float4* w1 = (const float4*)(Wih + (size_t)(i+H)*G3 + H);
  const float4* w2 = (const float4*)(Wih + (size_t)(i+2*H)*G3 + H);
  float d0=0,d1=0,d2=0;
#pragma unroll
  for(int k=lane;k<(2*H)/4;k+=64){
    float4 c=cv[k];
    float4 a=w0[k]; d0+=a.x*c.x+a.y*c.y+a.z*c.z+a.w*c.w;
    float4 b=w1[k]; d1+=b.x*c.x+b.y*c.y+b.z*c.z+b.w*c.w;
    float4 e=w2[k]; d2+=e.x*c.x+e.y*c.y+e.z*c.z+e.w*c.w;
  }
  const float4* u0 = (const float4*)(Whh + (size_t)i*H);
  const float4* u1 = (const float4*)(Whh + (size_t)(i+H)*H);
  const float4* u2 = (const float4*)(Whh + (size_t)(i+2*H)*H);
  float e0=0,e1=0,e2=0;
#pragma unroll
  for(int k=lane;k<H/4;k+=64){
    float4 h=hv[k];
    float4 a=u0[k]; e0+=a.x*h.x+a.y*h.y+a.z*h.z+a.w*h.w;
    float4 b=u1[k]; e1+=b.x*h.x+b.y*h.y+b.z*h.z+b.w*h.w;
    float4 c=u2[k]; e2+=c.x*h.x+c.y*h.y+c.z*h.z+c.w*h.w;
  }
  d0=wred_sum(d0); d1=wred_sum(d1); d2=wred_sum(d2);
  e0=wred_sum(e0); e1=wred_sum(e1); e2=wred_sum(e2);
  if(lane==0){
    const float* g = gie + (size_t)t*G3;
    float r = sigmoidf_((g[i]     + d0) + (e0 + bhh[i]));
    float z = sigmoidf_((g[i+H]   + d1) + (e1 + bhh[i+H]));
    float n = tanhf    ((g[i+2*H] + d2) + r*(e2 + bhh[i+2*H]));
    float hnew = (1.f-z)*n + z*hprev[i];
    hnext[i] = hnew;
    x4[(size_t)t*X4W + 3*H + i] = hnew;
    atomicAdd(&s_acc[t+1], hnew * v_dec[i]);
  }
}

// ---------------------------------------------------------------- log_softmax rows, in-place on d_out
__global__ __launch_bounds__(256) void logsoftmax_kernel(float* __restrict__ out){
  int t=blockIdx.x, tid=threadIdx.x, lane=tid&63, w=tid>>6;
  float4* r4 = (float4*)(out + (size_t)t*VOUT);
  float m=-INFINITY;
  for(int k=tid;k<VOUT/4;k+=256){
    float4 v=r4[k];
    m=fmaxf(m,fmaxf(fmaxf(v.x,v.y),fmaxf(v.z,v.w)));
  }
  __shared__ float wt[4];
  __shared__ float wt2[4];
  m=wred_max(m);
  if(lane==0) wt[w]=m;
  __syncthreads();
  float M=fmaxf(fmaxf(wt[0],wt[1]),fmaxf(wt[2],wt[3]));
  float s=0;
  for(int k=tid;k<VOUT/4;k+=256){
    float4 v=r4[k];
    s += expf(v.x-M)+expf(v.y-M)+expf(v.z-M)+expf(v.w-M);
  }
  s=wred_sum(s);
  if(lane==0) wt2[w]=s;
  __syncthreads();
  float lse = M + logf(wt2[0]+wt2[1]+wt2[2]+wt2[3]);
  for(int k=tid;k<VOUT/4;k+=256){
    float4 v=r4[k];
    v.x-=lse; v.y-=lse; v.z-=lse; v.w-=lse;
    r4[k]=v;
  }
}

// ================================================================ launch
extern "C" void kernel_launch(void* const* d_in, const int* in_sizes, int n_in,
                              void* d_out, int out_size, void* d_ws, size_t ws_size,
                              hipStream_t stream){
  const int*   src     = (const int*)d_in[0];
  const int*   tgt     = (const int*)d_in[1];
  const float* enc_emb = (const float*)d_in[2];
  const float* eWih_f  = (const float*)d_in[3];
  const float* eWhh_f  = (const float*)d_in[4];
  const float* ebih_f  = (const float*)d_in[5];
  const float* ebhh_f  = (const float*)d_in[6];
  const float* eWih_b  = (const float*)d_in[7];
  const float* eWhh_b  = (const float*)d_in[8];
  const float* ebih_b  = (const float*)d_in[9];
  const float* ebhh_b  = (const float*)d_in[10];
  const float* fcW     = (const float*)d_in[11];
  const float* fcb     = (const float*)d_in[12];
  const float* dec_emb = (const float*)d_in[13];
  const float* dWih    = (const float*)d_in[14];
  const float* dWhh    = (const float*)d_in[15];
  const float* dbih    = (const float*)d_in[16];
  const float* dbhh    = (const float*)d_in[17];
  const float* att_v   = (const float*)d_in[18];
  const float* outW    = (const float*)d_in[19];
  const float* outb    = (const float*)d_in[20];
  float* out = (float*)d_out;

  float* ws = (float*)d_ws;
  float* x_emb     = ws; ws += S*H;
  float* emb_all   = ws; ws += S*H;
  float* gi_f      = ws; ws += S*G3;
  float* gi_b      = ws; ws += S*G3;
  float* gie       = ws; ws += S*G3;
  float* hbuf      = ws; ws += 2*2*H;     // [2][2048] double buffer
  float* enc_outsT = ws; ws += 2*H*S;     // [2048][256]
  float* enc_score = ws; ws += S;
  float* s_acc     = ws; ws += S+4;       // s_acc[t] = h_t . v_dec
  float* dh        = ws; ws += 2*H;       // [2][1024] double buffer
  float* x4        = ws; ws += (size_t)S*X4W;
  size_t need = (size_t)(ws - (float*)d_ws) * sizeof(float);
  if(ws_size < need) return;  // workspace too small; fail loudly via wrong output

  const float* v_dec = att_v;
  const float* v_enc = att_v + H;

  prep_kernel<<<S,256,0,stream>>>(src,tgt,enc_emb,dec_emb,x_emb,emb_all,x4,hbuf,s_acc,enc_score);

  dim3 g1(G3/BM, S/BN);
  sgemm_nt_ct<<<g1,256,0,stream>>>(eWih_f,H, x_emb,H, ebih_f, gi_f,G3, H);
  sgemm_nt_ct<<<g1,256,0,stream>>>(eWih_b,H, x_emb,H, ebih_b, gi_b,G3, H);
  sgemm_nt_ct<<<g1,256,0,stream>>>(dWih,G3, emb_all,H, dbih, gie,G3, H);

  for(int t=0;t<S;t++){
    enc_step_kernel<<<512,256,0,stream>>>(t,eWhh_f,eWhh_b,ebhh_f,ebhh_b,gi_f,gi_b,
        hbuf + (size_t)(t&1)*2*H, hbuf + (size_t)((t+1)&1)*2*H,
        enc_outsT, enc_score, v_enc);
  }
  // final hb is in hbuf[0] second half
  dec_h0_kernel<<<256,256,0,stream>>>(fcW,fcb, hbuf + H, dh, s_acc, v_dec);

  for(int t=0;t<S;t++){
    dec_ctx_kernel<<<64,256,0,stream>>>(t, s_acc, enc_score, enc_outsT, x4);
    dec_gru_kernel<<<256,256,0,stream>>>(t, dWih, dWhh, gie, dbhh,
        dh + (size_t)(t&1)*H, dh + (size_t)((t+1)&1)*H, x4, s_acc, v_dec);
  }

  dim3 g2(VOUT/BM, S/BN);
  sgemm_nt_ct<<<g2,256,0,stream>>>(outW,X4W, x4,X4W, outb, out,VOUT, X4W);
  logsoftmax_kernel<<<S,256,0,stream>>>(out);
}